// Round 5
// baseline (130.729 us; speedup 1.0000x reference)
//
#include <hip/hip_runtime.h>
#include <cstdint>
#include <cstddef>

#define NB 64
#define NA 4096
#define ND 512

// ---------- JAX threefry2x32, key = jax.random.key(42) -> (0, 42) ----------
// Partitionable path: per flat element n, pair = (0, n); sub-64-bit widths
// XOR-fold the two output words: bits = x0_final ^ x1_final.  (verified R3)
__device__ __forceinline__ unsigned rotl32(unsigned x, int d){ return (x << d) | (x >> (32 - d)); }

__device__ unsigned threefry_bits(unsigned n){
  const unsigned ks0 = 0u;
  const unsigned ks1 = 42u;
  const unsigned ks2 = 0x1BD11BDAu ^ ks0 ^ ks1;
  unsigned x0 = 0u;
  unsigned x1 = n;
  x0 += ks0; x1 += ks1;
  const int r0[4] = {13, 15, 26, 6};
  const int r1[4] = {17, 29, 16, 24};
  #pragma unroll
  for (int j = 0; j < 4; j++){ x0 += x1; x1 = rotl32(x1, r0[j]); x1 ^= x0; }
  x0 += ks1; x1 += ks2 + 1u;
  #pragma unroll
  for (int j = 0; j < 4; j++){ x0 += x1; x1 = rotl32(x1, r1[j]); x1 ^= x0; }
  x0 += ks2; x1 += ks0 + 2u;
  #pragma unroll
  for (int j = 0; j < 4; j++){ x0 += x1; x1 = rotl32(x1, r0[j]); x1 ^= x0; }
  x0 += ks0; x1 += ks1 + 3u;
  #pragma unroll
  for (int j = 0; j < 4; j++){ x0 += x1; x1 = rotl32(x1, r1[j]); x1 ^= x0; }
  x0 += ks1; x1 += ks2 + 4u;
  #pragma unroll
  for (int j = 0; j < 4; j++){ x0 += x1; x1 = rotl32(x1, r0[j]); x1 ^= x0; }
  x0 += ks2; x1 += ks0 + 5u;
  return x0 ^ x1;
}

// ---------- logits + per-block min : one wave per 4 actions, 16/block ----------
__global__ __launch_bounds__(256) void dot_kernel(const float* __restrict__ s,
                                                  const float* __restrict__ ae,
                                                  float* __restrict__ logits,
                                                  float* __restrict__ minbuf){
  __shared__ float sm[4];
  int wave = threadIdx.x >> 6;
  int lane = threadIdx.x & 63;
  int blk  = blockIdx.x;            // 16384 blocks: b = blk>>8, 16 actions/block
  int b     = blk >> 8;
  int abase = ((blk & 255) << 4) | (wave << 2);   // 4 consecutive actions/wave
  const float* sr = s + b * ND;
  float4 s0 = *(const float4*)(sr + lane * 4);
  float4 s1 = *(const float4*)(sr + 256 + lane * 4);
  const float* ar = ae + ((size_t)(b * NA) + abase) * ND + lane * 4;
  // 8 independent 16B loads in flight per lane (4 actions x 2 halves)
  float4 a00 = *(const float4*)(ar);
  float4 a01 = *(const float4*)(ar + 256);
  float4 a10 = *(const float4*)(ar + 512);
  float4 a11 = *(const float4*)(ar + 768);
  float4 a20 = *(const float4*)(ar + 1024);
  float4 a21 = *(const float4*)(ar + 1280);
  float4 a30 = *(const float4*)(ar + 1536);
  float4 a31 = *(const float4*)(ar + 1792);
  float p0 = a00.x*s0.x + a00.y*s0.y + a00.z*s0.z + a00.w*s0.w
           + a01.x*s1.x + a01.y*s1.y + a01.z*s1.z + a01.w*s1.w;
  float p1 = a10.x*s0.x + a10.y*s0.y + a10.z*s0.z + a10.w*s0.w
           + a11.x*s1.x + a11.y*s1.y + a11.z*s1.z + a11.w*s1.w;
  float p2 = a20.x*s0.x + a20.y*s0.y + a20.z*s0.z + a20.w*s0.w
           + a21.x*s1.x + a21.y*s1.y + a21.z*s1.z + a21.w*s1.w;
  float p3 = a30.x*s0.x + a30.y*s0.y + a30.z*s0.z + a30.w*s0.w
           + a31.x*s1.x + a31.y*s1.y + a31.z*s1.z + a31.w*s1.w;
  #pragma unroll
  for (int off = 32; off > 0; off >>= 1){
    p0 += __shfl_xor(p0, off, 64);
    p1 += __shfl_xor(p1, off, 64);
    p2 += __shfl_xor(p2, off, 64);
    p3 += __shfl_xor(p3, off, 64);
  }
  if (lane == 0){
    float4 v = make_float4(p0, p1, p2, p3);
    *(float4*)(logits + (size_t)b * NA + abase) = v;
    sm[wave] = fminf(fminf(p0, p1), fminf(p2, p3));
  }
  __syncthreads();
  if (threadIdx.x == 0)
    minbuf[blk] = fminf(fminf(sm[0], sm[1]), fminf(sm[2], sm[3]));
}

// ---------- per row: detect mask dtype, fold min, mask-fill, top-5, sample ----------
__global__ __launch_bounds__(256) void row_kernel(float* __restrict__ out,
                                                  const void* __restrict__ maskp,
                                                  const float* __restrict__ minbuf,
                                                  const unsigned* __restrict__ alpha_raw){
  __shared__ float row[NA];
  __shared__ float su[4];
  __shared__ float rv[4]; __shared__ int ri[4];
  __shared__ float selv[5]; __shared__ int seli[5];
  __shared__ int s_mflag;
  __shared__ float s_fill;
  int b = blockIdx.x;
  int t = threadIdx.x;
  float* lrow = out + NB + (size_t)b * NA;
  const unsigned char* m8  = (const unsigned char*)maskp;
  const unsigned*      m32 = (const unsigned*)maskp;

  // -- mask dtype detect: first 4096 u32 words (16 KB, in-bounds either way).
  if (t == 0) s_mflag = 1;
  __syncthreads();
  for (int i = t; i < 4096; i += 256)
    if (m32[i] > 1u) s_mflag = 0;          // benign race, only 0 written

  // -- fold 16384 per-block mins (64/thread)
  float e = minbuf[t];
  for (int i = t + 256; i < 16384; i += 256) e = fminf(e, minbuf[i]);
  #pragma unroll
  for (int off = 32; off > 0; off >>= 1) e = fminf(e, __shfl_xor(e, off, 64));
  if ((t & 63) == 0) su[t >> 6] = e;
  __syncthreads();
  if (t == 0)
    s_fill = fminf(fminf(su[0], su[1]), fminf(su[2], su[3])) - 1.0f;
  __syncthreads();
  int   mflag = s_mflag;
  float fill  = s_fill;

  // -- mask-fill row (in place: masked logits are the returned logits)
  for (int a = t; a < NA; a += 256){
    int idx = b * NA + a;
    bool av = mflag ? (m32[idx] != 0u) : (m8[idx] != 0);
    float v = lrow[a];
    float mv = av ? v : fill;
    row[a]  = mv;
    lrow[a] = mv;
  }
  __syncthreads();

  // -- top-5 (5 passes, smallest-index tie-break like jax.lax.top_k)
  for (int k = 0; k < 5; k++){
    float bv = -INFINITY; int bi = 0x7FFFFFFF;
    for (int a = t; a < NA; a += 256){
      float v = row[a];
      if (v > bv){ bv = v; bi = a; }
    }
    #pragma unroll
    for (int off = 32; off > 0; off >>= 1){
      float ov = __shfl_xor(bv, off, 64);
      int   oi = __shfl_xor(bi, off, 64);
      if (ov > bv || (ov == bv && oi < bi)){ bv = ov; bi = oi; }
    }
    if ((t & 63) == 0){ rv[t >> 6] = bv; ri[t >> 6] = bi; }
    __syncthreads();
    if (t == 0){
      float fv = rv[0]; int fi = ri[0];
      for (int w = 1; w < 4; w++)
        if (rv[w] > fv || (rv[w] == fv && ri[w] < fi)){ fv = rv[w]; fi = ri[w]; }
      selv[k] = fv; seli[k] = fi;
      row[fi] = -INFINITY;
    }
    __syncthreads();
  }

  // -- gumbel-argmax sample over keep = available & top5
  if (t == 0){
    unsigned ab = *alpha_raw;   // int scalar or float bits — disambiguate
    float alpha = (ab < 0x00800000u) ? (float)(int)ab : __uint_as_float(ab);
    float best = -INFINITY; int ba = 0;
    for (int k = 0; k < 5; k++){
      int idx  = seli[k];
      int gidx = b * NA + idx;
      bool av = mflag ? (m32[gidx] != 0u) : (m8[gidx] != 0);
      if (!av) continue;
      unsigned bits = threefry_bits((unsigned)gidx);
      float f = __uint_as_float((bits >> 9) | 0x3F800000u) - 1.0f;  // [0,1)
      const float tiny = 1.17549435e-38f;
      float u = fmaxf(tiny, f + tiny);
      float g = -logf(-logf(u));
      // argmax(log softmax_renorm) + g  ==  argmax(l/alpha + g) over keep set
      float sc = selv[k] / alpha + g;
      if (sc > best){ best = sc; ba = idx; }
    }
    out[b] = (float)ba;
  }
}

extern "C" void kernel_launch(void* const* d_in, const int* in_sizes, int n_in,
                              void* d_out, int out_size, void* d_ws, size_t ws_size,
                              hipStream_t stream){
  const float*    s     = (const float*)d_in[0];
  const float*    ae    = (const float*)d_in[1];
  const void*     mask  = d_in[2];
  const unsigned* alpha = (const unsigned*)d_in[3];
  float* out = (float*)d_out;
  float* ws  = (float*)d_ws;

  hipLaunchKernelGGL(dot_kernel, dim3(NB * NA / 16), dim3(256), 0, stream, s, ae, out + NB, ws);
  hipLaunchKernelGGL(row_kernel, dim3(NB),           dim3(256), 0, stream, out, mask, ws, alpha);
}